// Round 8
// baseline (501.444 us; speedup 1.0000x reference)
//
#include <hip/hip_runtime.h>
#include <hip/hip_bf16.h>
#include <math.h>

// ---------------------------------------------------------------------------
// CrossPath: dual cross-attention block, MI355X (gfx950).
//   B=4, N=2304, C=256, H=8, D=32, out = 2 x [B,C,96,96] float32
// Inputs float32 (runtime-sniffed). Internal: bf16 MFMA, fp32 accumulation.
// beta cancels in softmax; scores bounded -> no-max softmax in exp2 domain.
// R8: x pre-converted to bf16 once; merged-QKV GEMM with 128x128 tile and
// K pre-scaled by scale*log2e; attention 2-wave blocks with 32 q/wave
// (2x MFMA density); packed v_cvt_pk_bf16_f32; P-scratch stride 88.
// ---------------------------------------------------------------------------

typedef __attribute__((ext_vector_type(8))) short short8;   // 8 bf16 = 4 VGPRs
typedef __attribute__((ext_vector_type(4))) float f32x4;

#define MFMA16(a, b, c) __builtin_amdgcn_mfma_f32_16x16x32_bf16((a), (b), (c), 0, 0, 0)

__device__ __forceinline__ float bf2f(ushort u) {
    union { unsigned u; float f; } x; x.u = ((unsigned)u) << 16; return x.f;
}
__device__ __forceinline__ ushort f2bf(float f) {
    union { float f; unsigned u; } x; x.f = f;
    unsigned u = x.u;
    return (ushort)((u + 0x7fffu + ((u >> 16) & 1u)) >> 16);   // RNE
}
__device__ __forceinline__ unsigned pkbf(float a, float b) {   // packed RNE cvt
    union { __hip_bfloat162 h; unsigned u; } cv;
    cv.h = __float22bfloat162_rn(make_float2(a, b));
    return cv.u;
}

__global__ void sniff_kernel(const ushort* __restrict__ x, int* __restrict__ flag)
{
    int lane = threadIdx.x;
    ushort u = x[lane * 2];
    int e = (u >> 7) & 0xFF;
    int outlier = (e < 100 || e > 135) ? 1 : 0;
    unsigned long long m = __ballot(outlier);
    if (lane == 0) *flag = (__popcll(m) >= 16) ? 1 : 0;
}

// ---------------------------------------------------------------------------
// Canonicalize the 12 weight/param arrays to bf16 (q+kv merged per input).
// ---------------------------------------------------------------------------
__global__ __launch_bounds__(256) void convert_params(
    const void* s0, const void* s1, const void* s2, const void* s3,
    const void* s4, const void* s5, const void* s6, const void* s7,
    const void* s8, const void* s9, const void* s10, const void* s11,
    ushort* __restrict__ dst, const int* __restrict__ flag)
{
    int idx = blockIdx.x * 256 + threadIdx.x;
    if (idx >= 525824) return;
    const void* src; int off;
    if      (idx < 65536)  { src = s0;  off = idx; }
    else if (idx < 196608) { src = s1;  off = idx - 65536; }
    else if (idx < 262144) { src = s2;  off = idx - 196608; }
    else if (idx < 393216) { src = s3;  off = idx - 262144; }
    else if (idx < 458752) { src = s4;  off = idx - 393216; }
    else if (idx < 524288) { src = s5;  off = idx - 458752; }
    else if (idx < 524544) { src = s6;  off = idx - 524288; }
    else if (idx < 524800) { src = s7;  off = idx - 524544; }
    else if (idx < 525056) { src = s8;  off = idx - 524800; }
    else if (idx < 525312) { src = s9;  off = idx - 525056; }
    else if (idx < 525568) { src = s10; off = idx - 525312; }
    else                   { src = s11; off = idx - 525568; }
    ushort v = (*flag) ? f2bf(((const float*)src)[off])
                       : ((const ushort*)src)[off];
    dst[idx] = v;
}

// ---------------------------------------------------------------------------
// Convert one activation tensor (f32-or-bf16 per flag) to bf16, 8 elems/thr.
// ---------------------------------------------------------------------------
__global__ __launch_bounds__(256) void convert_x(
    const void* __restrict__ src, ushort* __restrict__ dst,
    const int* __restrict__ flag)
{
    int idx = (blockIdx.x * 256 + threadIdx.x) * 8;   // n = 2359296
    if (*flag) {
        const float* s = (const float*)src + idx;
        float4 a = *(const float4*)s;
        float4 b = *(const float4*)(s + 4);
        uint4 o;
        o.x = pkbf(a.x, a.y); o.y = pkbf(a.z, a.w);
        o.z = pkbf(b.x, b.y); o.w = pkbf(b.z, b.w);
        *(uint4*)(dst + idx) = o;
    } else {
        *(uint4*)(dst + idx) = *(const uint4*)((const ushort*)src + idx);
    }
}

// ---------------------------------------------------------------------------
// Merged QKV projection: [9216,256]x[768,256]^T. Tile 128x128, 4 waves,
// 16 MFMA / BK=32 step. Epilogue (wave-uniform on n0): n0<256 -> Qo row-major;
// n0<512 -> Kh[b][h][tok][32] PRE-SCALED by SC; else Vt[b][h][d][2304] (b64).
// ---------------------------------------------------------------------------
__global__ __launch_bounds__(256) void gemm_qkv(
    const ushort* __restrict__ X, const ushort* __restrict__ W,
    ushort* __restrict__ Qo, ushort* __restrict__ Kh, ushort* __restrict__ Vt)
{
    __shared__ __align__(16) ushort As[128][40];
    __shared__ __align__(16) ushort Bs[128][40];

    const int m0 = blockIdx.x * 128;
    const int n0 = blockIdx.y * 128;
    const int tid = threadIdx.x;
    const int w = tid >> 6, lane = tid & 63;
    const int lm = lane & 15, quad = lane >> 4;
    const float SC = 0.17677669529663687f * 1.4426950408889634f;

    const f32x4 Z4 = {0.f, 0.f, 0.f, 0.f};
    f32x4 acc[2][8];
    for (int i = 0; i < 2; i++)
        for (int j = 0; j < 8; j++) acc[i][j] = Z4;

    for (int k0 = 0; k0 < 256; k0 += 32) {
        __syncthreads();
        for (int cc = 0; cc < 2; cc++) {
            int c = tid + cc * 256;
            int row = c >> 2, off = (c & 3) * 8;
            *(uint4*)&As[row][off] =
                *(const uint4*)(X + (size_t)(m0 + row) * 256 + k0 + off);
            *(uint4*)&Bs[row][off] =
                *(const uint4*)(W + (size_t)(n0 + row) * 256 + k0 + off);
        }
        __syncthreads();

        short8 af[2], wf[8];
        for (int mt = 0; mt < 2; mt++)
            af[mt] = *(const short8*)&As[w * 32 + mt * 16 + lm][quad * 8];
        for (int nt = 0; nt < 8; nt++)
            wf[nt] = *(const short8*)&Bs[nt * 16 + lm][quad * 8];
        for (int mt = 0; mt < 2; mt++)
            for (int nt = 0; nt < 8; nt++)
                acc[mt][nt] = MFMA16(af[mt], wf[nt], acc[mt][nt]);
    }

    for (int mt = 0; mt < 2; mt++) {
        int grow = m0 + w * 32 + mt * 16 + quad * 4;
        int bb = grow / 2304;
        int tok = grow - bb * 2304;          // 4-aligned, same bb for r=0..3
        if (n0 < 256) {
            for (int nt = 0; nt < 8; nt++) {
                int col = n0 + nt * 16 + lm;
                for (int r = 0; r < 4; r++)
                    Qo[(size_t)(grow + r) * 256 + col] = f2bf(acc[mt][nt][r]);
            }
        } else if (n0 < 512) {
            for (int nt = 0; nt < 8; nt++) {
                int c2 = n0 - 256 + nt * 16 + lm;
                int hh = c2 >> 5, d = c2 & 31;
                for (int r = 0; r < 4; r++)
                    Kh[(((size_t)bb * 8 + hh) * 2304 + tok + r) * 32 + d]
                        = f2bf(acc[mt][nt][r] * SC);
            }
        } else {
            for (int nt = 0; nt < 8; nt++) {
                int c2 = n0 - 512 + nt * 16 + lm;
                int hh = c2 >> 5, d = c2 & 31;
                uint2 pk;
                pk.x = pkbf(acc[mt][nt][0], acc[mt][nt][1]);
                pk.y = pkbf(acc[mt][nt][2], acc[mt][nt][3]);
                *(uint2*)&Vt[(((size_t)bb * 8 + hh) * 32 + d) * 2304 + tok] = pk;
            }
        }
    }
}

// ---------------------------------------------------------------------------
// Output projection: [9216,256]x[256,256]^T + bias + relu. Tile 64x64.
// ---------------------------------------------------------------------------
__global__ __launch_bounds__(256) void gemm_out(
    const ushort* __restrict__ A, const ushort* __restrict__ W,
    ushort* __restrict__ C, const ushort* __restrict__ bias)
{
    __shared__ __align__(16) ushort As[64][40];
    __shared__ __align__(16) ushort Ws[64][40];

    const int m0 = blockIdx.x * 64;
    const int n0 = blockIdx.y * 64;
    const int tid = threadIdx.x;
    const int w = tid >> 6, lane = tid & 63;
    const int lm = lane & 15, quad = lane >> 4;
    const int row = tid >> 2, off = (tid & 3) * 8;

    const f32x4 Z4 = {0.f, 0.f, 0.f, 0.f};
    f32x4 acc[4];
    for (int j = 0; j < 4; j++) acc[j] = Z4;

    for (int k0 = 0; k0 < 256; k0 += 32) {
        __syncthreads();
        *(uint4*)&As[row][off] =
            *(const uint4*)(A + (size_t)(m0 + row) * 256 + k0 + off);
        *(uint4*)&Ws[row][off] =
            *(const uint4*)(W + (size_t)(n0 + row) * 256 + k0 + off);
        __syncthreads();

        short8 af = *(const short8*)&As[w * 16 + lm][quad * 8];
        for (int nt = 0; nt < 4; nt++) {
            short8 wf = *(const short8*)&Ws[nt * 16 + lm][quad * 8];
            acc[nt] = MFMA16(af, wf, acc[nt]);
        }
    }

    int grow = m0 + w * 16 + quad * 4;
    for (int nt = 0; nt < 4; nt++) {
        int col = n0 + nt * 16 + lm;
        float bv = bf2f(bias[col]);
        for (int r = 0; r < 4; r++) {
            float v = fmaxf(acc[nt][r] + bv, 0.f);
            C[(size_t)(grow + r) * 256 + col] = f2bf(v);
        }
    }
}

// ---------------------------------------------------------------------------
// Flash cross-attention, S^T form, no-max softmax. K pre-scaled by SC.
// Block = 128 thr (2 waves); wave owns 32 q-rows (2 fragments); grid 36x32.
// P^T via per-wave LDS (stride 88: b64 writes & b128 reads bank-balanced).
// ---------------------------------------------------------------------------
__global__ __launch_bounds__(128) void attn_kernel(
    const ushort* __restrict__ Q, const ushort* __restrict__ Kh,
    const ushort* __restrict__ Vt, ushort* __restrict__ O)
{
    __shared__ __align__(16) ushort Ksh[64][40];        // [key][d]
    __shared__ __align__(16) ushort Vsh[32][72];        // [d][tok]
    __shared__ __align__(16) ushort Pl[2][2][16][88];   // [wave][qfrag][q][key]

    const int qb = blockIdx.x, bh = blockIdx.y;
    const int b = bh >> 3, h = bh & 7;
    const int tid = threadIdx.x;
    const int w = tid >> 6, lane = tid & 63;
    const int lm = lane & 15, quad = lane >> 4;
    const f32x4 Z4 = {0.f, 0.f, 0.f, 0.f};

    const int q0 = qb * 64 + w * 32;
    short8 qf[2];
    for (int i = 0; i < 2; i++)
        qf[i] = *(const short8*)(Q + ((size_t)b * 2304 + q0 + i * 16 + lm) * 256
                                 + h * 32 + quad * 8);

    f32x4 o_acc[2][2];
    for (int i = 0; i < 2; i++) { o_acc[i][0] = Z4; o_acc[i][1] = Z4; }
    float l[2] = {0.f, 0.f};

    const ushort* Khb = Kh + (size_t)bh * 2304 * 32;
    const ushort* Vtb = Vt + (size_t)bh * 32 * 2304;

    for (int kc = 0; kc < 36; kc++) {
        const int kbase = kc * 64;
        __syncthreads();
        for (int cc = 0; cc < 2; cc++) {
            int c = tid + cc * 128;
            int kr = c >> 2, ko = (c & 3) * 8;          // K: 64 rows x 32 d
            *(uint4*)&Ksh[kr][ko] =
                *(const uint4*)(Khb + (size_t)(kbase + kr) * 32 + ko);
            int vr = c >> 3, vo = (c & 7) * 8;          // V: 32 d x 64 tok
            *(uint4*)&Vsh[vr][vo] =
                *(const uint4*)(Vtb + (size_t)vr * 2304 + kbase + vo);
        }
        __syncthreads();

        short8 kf[4];
        for (int t = 0; t < 4; t++)
            kf[t] = *(const short8*)&Ksh[t * 16 + lm][quad * 8];

        // S^T (pre-scaled): tile t keys t*16+quad*4+r, col q=lm
        f32x4 s[2][4];
        for (int i = 0; i < 2; i++)
            for (int t = 0; t < 4; t++)
                s[i][t] = MFMA16(kf[t], qf[i], Z4);

        // p = exp2(s); per-lane l; packed bf16 -> per-wave P^T LDS
        for (int i = 0; i < 2; i++)
            for (int t = 0; t < 4; t++) {
                float p0 = exp2f(s[i][t][0]);
                float p1 = exp2f(s[i][t][1]);
                float p2 = exp2f(s[i][t][2]);
                float p3 = exp2f(s[i][t][3]);
                l[i] += (p0 + p1) + (p2 + p3);
                uint2 pk;
                pk.x = pkbf(p0, p1);
                pk.y = pkbf(p2, p3);
                *(uint2*)&Pl[w][i][lm][t * 16 + quad * 4] = pk;
            }
        asm volatile("s_waitcnt lgkmcnt(0)" ::: "memory");  // own-wave P done

        // O^T += V^T * P^T  (V frags shared across both q-fragments)
        for (int g = 0; g < 2; g++) {
            short8 vf[2];
            for (int dt = 0; dt < 2; dt++)
                vf[dt] = *(const short8*)&Vsh[dt * 16 + lm][g * 32 + quad * 8];
            for (int i = 0; i < 2; i++) {
                short8 pf = *(const short8*)&Pl[w][i][lm][g * 32 + quad * 8];
                for (int dt = 0; dt < 2; dt++)
                    o_acc[i][dt] = MFMA16(vf[dt], pf, o_acc[i][dt]);
            }
        }
    }

    for (int i = 0; i < 2; i++) {
        float li = l[i];
        li += __shfl_xor(li, 16, 64);
        li += __shfl_xor(li, 32, 64);
        float rl = 1.f / li;
        for (int dt = 0; dt < 2; dt++) {
            uint2 pk;
            pk.x = pkbf(o_acc[i][dt][0] * rl, o_acc[i][dt][1] * rl);
            pk.y = pkbf(o_acc[i][dt][2] * rl, o_acc[i][dt][3] * rl);
            *(uint2*)(O + ((size_t)b * 2304 + q0 + i * 16 + lm) * 256
                      + h * 32 + dt * 16 + quad * 4) = pk;
        }
    }
}

// ---------------------------------------------------------------------------
// LayerNorm over C=256, one wave per token.
// ---------------------------------------------------------------------------
__global__ __launch_bounds__(256) void ln_kernel(
    const ushort* __restrict__ Z, const ushort* __restrict__ G,
    const ushort* __restrict__ Bt, ushort* __restrict__ Y)
{
    int tok = blockIdx.x * 4 + (threadIdx.x >> 6);
    int lane = threadIdx.x & 63;
    const ushort* z = Z + (size_t)tok * 256 + lane * 4;
    ushort4 v = *(const ushort4*)z;
    float x0 = bf2f(v.x), x1 = bf2f(v.y), x2 = bf2f(v.z), x3 = bf2f(v.w);
    float s = x0 + x1 + x2 + x3;
    float q = x0 * x0 + x1 * x1 + x2 * x2 + x3 * x3;
    for (int off = 1; off < 64; off <<= 1) {
        s += __shfl_xor(s, off, 64);
        q += __shfl_xor(q, off, 64);
    }
    float mu = s * (1.f / 256.f);
    float var = q * (1.f / 256.f) - mu * mu;
    float rs = rsqrtf(var + 1e-5f);
    const ushort* g4 = G + lane * 4;
    const ushort* b4 = Bt + lane * 4;
    ushort4 o;
    o.x = f2bf((x0 - mu) * rs * bf2f(g4[0]) + bf2f(b4[0]));
    o.y = f2bf((x1 - mu) * rs * bf2f(g4[1]) + bf2f(b4[1]));
    o.z = f2bf((x2 - mu) * rs * bf2f(g4[2]) + bf2f(b4[2]));
    o.w = f2bf((x3 - mu) * rs * bf2f(g4[3]) + bf2f(b4[3]));
    *(ushort4*)(Y + (size_t)tok * 256 + lane * 4) = o;
}

// ---------------------------------------------------------------------------
// Bilinear 2x upsample, half-pixel + edge clamp. Y bf16 -> out FLOAT32.
// ---------------------------------------------------------------------------
__global__ __launch_bounds__(256) void upsample_kernel(
    const ushort* __restrict__ Y, float* __restrict__ out)
{
    int idx = blockIdx.x * 256 + threadIdx.x;
    int oj = idx % 96;
    int t = idx / 96;
    int oi = t % 96;
    t /= 96;
    int c = t & 255;
    int b = t >> 8;
    float fi = oi * 0.5f - 0.25f;
    float fj = oj * 0.5f - 0.25f;
    int i0 = (int)floorf(fi); float wi = fi - (float)i0;
    int j0 = (int)floorf(fj); float wj = fj - (float)j0;
    int i1 = i0 + 1 < 47 ? i0 + 1 : 47;
    int j1 = j0 + 1 < 47 ? j0 + 1 : 47;
    i0 = i0 > 0 ? i0 : 0;
    j0 = j0 > 0 ? j0 : 0;
    const ushort* base = Y + (size_t)b * 2304 * 256 + c;
    float v00 = bf2f(base[(size_t)(i0 * 48 + j0) * 256]);
    float v01 = bf2f(base[(size_t)(i0 * 48 + j1) * 256]);
    float v10 = bf2f(base[(size_t)(i1 * 48 + j0) * 256]);
    float v11 = bf2f(base[(size_t)(i1 * 48 + j1) * 256]);
    float val = (1.f - wi) * ((1.f - wj) * v00 + wj * v01)
              + wi * ((1.f - wj) * v10 + wj * v11);
    out[idx] = val;
}

// ---------------------------------------------------------------------------
extern "C" void kernel_launch(void* const* d_in, const int* in_sizes, int n_in,
                              void* d_out, int out_size, void* d_ws, size_t ws_size,
                              hipStream_t stream)
{
    (void)in_sizes; (void)n_in; (void)out_size; (void)ws_size;

    // ---- ws plan (~29.4 MB) ----
    ushort* ws  = (ushort*)d_ws;
    ushort* Q1  = ws;                         // [9216,256]
    ushort* Q2  = Q1  + 2359296;
    ushort* KV1 = Q2  + 2359296;              // Kh1 + Vt1
    ushort* KV2 = KV1 + 4718592;              // Kh2 + Vt2
    ushort* wc  = KV2 + 4718592;              // canonical params
    int*    dflag = (int*)(wc + 525824);

    ushort* cqkv1w = wc;                      // [768,256]
    ushort* cqkv2w = wc + 196608;
    ushort* cp1w  = wc + 393216;
    ushort* cp2w  = wc + 458752;
    ushort* cp1b  = wc + 524288;
    ushort* cp2b  = wc + 524544;
    ushort* cg1   = wc + 524800;
    ushort* cb1   = wc + 525056;
    ushort* cg2   = wc + 525312;
    ushort* cb2   = wc + 525568;

    // ---- d_out staging (all dead before the final upsample writes) ----
    float*  outf = (float*)d_out;
    ushort* O1  = (ushort*)d_out;             // [0, 4.7MB)
    ushort* O2  = O1 + 2359296;
    ushort* X1b = O1 + 4718592;               // bf16 x1 [9.4MB, 14.2MB)
    ushort* X2b = O1 + 7077888;               // bf16 x2 [14.2MB, 18.9MB)
    ushort* Z1  = KV2;                        // KV2 dead after attn1
    ushort* Z2  = KV2 + 2359296;
    ushort* Y1  = Q1;                         // Q1/Q2 dead after attns
    ushort* Y2  = Q2;

    dim3 b256(256), b128(128);
    sniff_kernel<<<dim3(1), dim3(64), 0, stream>>>((const ushort*)d_in[0], dflag);
    convert_params<<<dim3(2054), b256, 0, stream>>>(
        d_in[2], d_in[3], d_in[4], d_in[5], d_in[8], d_in[10],
        d_in[9], d_in[11], d_in[12], d_in[13], d_in[14], d_in[15],
        wc, dflag);
    convert_x<<<dim3(1152), b256, 0, stream>>>(d_in[0], X1b, dflag);
    convert_x<<<dim3(1152), b256, 0, stream>>>(d_in[1], X2b, dflag);

    // Merged QKV projections (Q plain; K per-head pre-scaled; V transposed)
    gemm_qkv<<<dim3(72, 6), b256, 0, stream>>>(X1b, cqkv1w, Q1, KV1, KV1 + 2359296);
    gemm_qkv<<<dim3(72, 6), b256, 0, stream>>>(X2b, cqkv2w, Q2, KV2, KV2 + 2359296);
    // Cross attention
    attn_kernel<<<dim3(36, 32), b128, 0, stream>>>(Q1, KV2, KV2 + 2359296, O1);
    attn_kernel<<<dim3(36, 32), b128, 0, stream>>>(Q2, KV1, KV1 + 2359296, O2);
    // Output projection + bias + ReLU
    gemm_out<<<dim3(144, 4), b256, 0, stream>>>(O1, cp1w, Z1, cp1b);
    gemm_out<<<dim3(144, 4), b256, 0, stream>>>(O2, cp2w, Z2, cp2b);
    // LayerNorm
    ln_kernel<<<dim3(2304), b256, 0, stream>>>(Z1, cg1, cb1, Y1);
    ln_kernel<<<dim3(2304), b256, 0, stream>>>(Z2, cg2, cb2, Y2);
    // Bilinear 2x upsample into d_out (float32)
    upsample_kernel<<<dim3(36864), b256, 0, stream>>>(Y1, outf);
    upsample_kernel<<<dim3(36864), b256, 0, stream>>>(Y2, outf + 9437184);
}